// Round 1
// baseline (491.049 us; speedup 1.0000x reference)
//
#include <hip/hip_runtime.h>
#include <hip/hip_bf16.h>

#define NNODES 25000
#define NEDGES 400000
#define DIM 128
#define NGRAPHS 512
#define DOUT 10

// ---------------- CSR build ----------------

__global__ __launch_bounds__(256) void k_deg(const int* __restrict__ dst,
                                             int* __restrict__ deg) {
  int i = blockIdx.x * 256 + threadIdx.x;
  if (i < NEDGES) atomicAdd(&deg[dst[i]], 1);
}

__global__ __launch_bounds__(1024) void k_scan(const int* __restrict__ deg,
                                               int* __restrict__ offs,
                                               int* __restrict__ cursor) {
  __shared__ int tsum[1024];
  int tid = threadIdx.x;
  const int per = (NNODES + 1023) / 1024;  // 25
  int start = tid * per; if (start > NNODES) start = NNODES;
  int end = start + per; if (end > NNODES) end = NNODES;
  int s = 0;
  for (int i = start; i < end; ++i) s += deg[i];
  tsum[tid] = s;
  __syncthreads();
  // Hillis-Steele inclusive scan over thread sums
  for (int off = 1; off < 1024; off <<= 1) {
    int v = (tid >= off) ? tsum[tid - off] : 0;
    __syncthreads();
    tsum[tid] += v;
    __syncthreads();
  }
  int run = (tid == 0) ? 0 : tsum[tid - 1];
  for (int i = start; i < end; ++i) {
    offs[i] = run;
    cursor[i] = run;
    run += deg[i];
  }
  if (tid == 1023) offs[NNODES] = run;  // = NEDGES
}

__global__ __launch_bounds__(256) void k_scatter(const int* __restrict__ src,
                                                 const int* __restrict__ dst,
                                                 int* __restrict__ cursor,
                                                 int* __restrict__ csr) {
  int i = blockIdx.x * 256 + threadIdx.x;
  if (i < NEDGES) {
    int p = atomicAdd(&cursor[dst[i]], 1);
    csr[p] = src[i];
  }
}

// ---------------- GIN aggregation: agg[i] = (1+eps)*h[i] + sum_{j in N(i)} h[j] ----------------

__global__ __launch_bounds__(128) void k_agg(const float* __restrict__ h,
                                             const int* __restrict__ offs,
                                             const int* __restrict__ csr,
                                             const float* __restrict__ epsp, int layer,
                                             float* __restrict__ agg) {
  int node = blockIdx.x;
  int t = threadIdx.x;  // 0..127 feature
  float eps1 = 1.0f + epsp[layer];
  int s = offs[node], e = offs[node + 1];
  float acc = eps1 * h[node * DIM + t];
  int j = s;
  for (; j + 1 < e; j += 2) {
    int s0 = csr[j], s1 = csr[j + 1];
    float v0 = h[s0 * DIM + t];
    float v1 = h[s1 * DIM + t];
    acc += v0;
    acc += v1;
  }
  if (j < e) acc += h[csr[j] * DIM + t];
  agg[node * DIM + t] = acc;
}

// ---------------- Fused MLP: relu( relu(bn(agg@W1+b1)) @ W2 + b2 ) ----------------

#define RROWS 16

__global__ __launch_bounds__(128) void k_mlp(const float* __restrict__ agg,
                                             const float* __restrict__ W1,
                                             const float* __restrict__ b1,
                                             const float* __restrict__ gamma,
                                             const float* __restrict__ beta,
                                             const float* __restrict__ rmean,
                                             const float* __restrict__ rvar,
                                             const float* __restrict__ W2,
                                             const float* __restrict__ b2,
                                             float* __restrict__ hout) {
  __shared__ float rbuf[RROWS][DIM];
  __shared__ float zbuf[RROWS][DIM];
  int t = threadIdx.x;  // output column
  int r0 = blockIdx.x * RROWS;
  int nr = NNODES - r0; if (nr > RROWS) nr = RROWS;

  // fold BN into scale/shift for column t (bias b1 included in acc)
  float bn_scale = gamma[t] * rsqrtf(rvar[t] + 1e-5f);
  float bn_shift = beta[t] - rmean[t] * bn_scale;
  float bias1 = b1[t];
  float bias2 = b2[t];

  // stage input rows
  for (int i = t; i < nr * DIM; i += 128) {
    ((float*)rbuf)[i] = agg[r0 * DIM + i];
  }
  __syncthreads();

  // GEMM1 + BN + ReLU
  float acc[RROWS];
#pragma unroll
  for (int r = 0; r < RROWS; ++r) acc[r] = bias1;
#pragma unroll 4
  for (int k = 0; k < DIM; ++k) {
    float w = W1[k * DIM + t];
#pragma unroll
    for (int r = 0; r < RROWS; ++r) acc[r] = fmaf(rbuf[r][k], w, acc[r]);
  }
#pragma unroll
  for (int r = 0; r < RROWS; ++r) {
    float z = fmaxf(fmaf(acc[r], bn_scale, bn_shift), 0.0f);
    zbuf[r][t] = z;
  }
  __syncthreads();

  // GEMM2 + ReLU
  float acc2[RROWS];
#pragma unroll
  for (int r = 0; r < RROWS; ++r) acc2[r] = bias2;
#pragma unroll 4
  for (int k = 0; k < DIM; ++k) {
    float w = W2[k * DIM + t];
#pragma unroll
    for (int r = 0; r < RROWS; ++r) acc2[r] = fmaf(zbuf[r][k], w, acc2[r]);
  }
  for (int r = 0; r < nr; ++r) {
    hout[(r0 + r) * DIM + t] = fmaxf(acc2[r], 0.0f);
  }
}

// ---------------- mean-pool per graph + final linear ----------------

__device__ inline int lower_bound_i(const int* a, int n, int key) {
  int lo = 0, hi = n;
  while (lo < hi) {
    int m = (lo + hi) >> 1;
    if (a[m] < key) lo = m + 1; else hi = m;
  }
  return lo;
}

__global__ __launch_bounds__(128) void k_pool(const float* __restrict__ h,
                                              const int* __restrict__ batch,
                                              const float* __restrict__ Wout,
                                              const float* __restrict__ bout,
                                              float* __restrict__ out) {
  int g = blockIdx.x;
  int t = threadIdx.x;
  int lo = lower_bound_i(batch, NNODES, g);
  int hi = lower_bound_i(batch, NNODES, g + 1);
  float s = 0.0f;
  for (int i = lo; i < hi; ++i) s += h[i * DIM + t];
  float cnt = (hi > lo) ? (float)(hi - lo) : 1.0f;
  __shared__ float pooled[DIM];
  pooled[t] = s / cnt;
  __syncthreads();
  if (t < DOUT) {
    float acc = bout[t];
#pragma unroll 4
    for (int k = 0; k < DIM; ++k) acc = fmaf(pooled[k], Wout[k * DOUT + t], acc);
    out[g * DOUT + t] = acc;
  }
}

// ---------------- launch ----------------

extern "C" void kernel_launch(void* const* d_in, const int* in_sizes, int n_in,
                              void* d_out, int out_size, void* d_ws, size_t ws_size,
                              hipStream_t stream) {
  const float* x     = (const float*)d_in[0];
  const int*   ei    = (const int*)d_in[1];   // [2][NEDGES]: row0 src, row1 dst
  const int*   batch = (const int*)d_in[2];
  const float* W1    = (const float*)d_in[3];
  const float* b1    = (const float*)d_in[4];
  const float* gamma = (const float*)d_in[5];
  const float* beta  = (const float*)d_in[6];
  const float* rmean = (const float*)d_in[7];
  const float* rvar  = (const float*)d_in[8];
  const float* W2    = (const float*)d_in[9];
  const float* b2    = (const float*)d_in[10];
  const float* eps   = (const float*)d_in[11];
  const float* Wout  = (const float*)d_in[12];
  const float* bout  = (const float*)d_in[13];
  float* out = (float*)d_out;

  const int* src = ei;
  const int* dst = ei + NEDGES;

  char* ws = (char*)d_ws;
  size_t o = 0;
  auto alloc = [&](size_t bytes) -> void* {
    o = (o + 255) & ~(size_t)255;
    void* p = ws + o;
    o += bytes;
    return p;
  };
  int*   deg    = (int*)alloc(NNODES * sizeof(int));
  int*   offs   = (int*)alloc((NNODES + 1) * sizeof(int));
  int*   cursor = (int*)alloc(NNODES * sizeof(int));
  int*   csr    = (int*)alloc(NEDGES * sizeof(int));
  float* agg    = (float*)alloc((size_t)NNODES * DIM * sizeof(float));
  float* hA     = (float*)alloc((size_t)NNODES * DIM * sizeof(float));
  float* hB     = (float*)alloc((size_t)NNODES * DIM * sizeof(float));

  hipMemsetAsync(deg, 0, NNODES * sizeof(int), stream);
  k_deg<<<(NEDGES + 255) / 256, 256, 0, stream>>>(dst, deg);
  k_scan<<<1, 1024, 0, stream>>>(deg, offs, cursor);
  k_scatter<<<(NEDGES + 255) / 256, 256, 0, stream>>>(src, dst, cursor, csr);

  const float* hin = x;
  float* houts[3] = {hA, hB, hA};
  for (int l = 0; l < 3; ++l) {
    k_agg<<<NNODES, 128, 0, stream>>>(hin, offs, csr, eps, l, agg);
    k_mlp<<<(NNODES + RROWS - 1) / RROWS, 128, 0, stream>>>(
        agg, W1 + (size_t)l * DIM * DIM, b1 + l * DIM, gamma + l * DIM,
        beta + l * DIM, rmean + l * DIM, rvar + l * DIM,
        W2 + (size_t)l * DIM * DIM, b2 + l * DIM, houts[l]);
    hin = houts[l];
  }
  k_pool<<<NGRAPHS, 128, 0, stream>>>(hin, batch, Wout, bout, out);
}

// Round 2
// 385.146 us; speedup vs baseline: 1.2750x; 1.2750x over previous
//
#include <hip/hip_runtime.h>
#include <hip/hip_bf16.h>

#define NNODES 25000
#define NEDGES 400000
#define DIM 128
#define NGRAPHS 512
#define DOUT 10

// ---------------- CSR build ----------------

__global__ __launch_bounds__(256) void k_deg(const int* __restrict__ dst,
                                             int* __restrict__ deg) {
  int i = blockIdx.x * 256 + threadIdx.x;
  if (i < NEDGES) atomicAdd(&deg[dst[i]], 1);
}

__global__ __launch_bounds__(1024) void k_scan(const int* __restrict__ deg,
                                               int* __restrict__ offs,
                                               int* __restrict__ cursor) {
  __shared__ int tsum[1024];
  int tid = threadIdx.x;
  const int per = (NNODES + 1023) / 1024;  // 25
  int start = tid * per; if (start > NNODES) start = NNODES;
  int end = start + per; if (end > NNODES) end = NNODES;
  int s = 0;
  for (int i = start; i < end; ++i) s += deg[i];
  tsum[tid] = s;
  __syncthreads();
  for (int off = 1; off < 1024; off <<= 1) {
    int v = (tid >= off) ? tsum[tid - off] : 0;
    __syncthreads();
    tsum[tid] += v;
    __syncthreads();
  }
  int run = (tid == 0) ? 0 : tsum[tid - 1];
  for (int i = start; i < end; ++i) {
    offs[i] = run;
    cursor[i] = run;
    run += deg[i];
  }
  if (tid == 1023) offs[NNODES] = run;
}

__global__ __launch_bounds__(256) void k_scatter(const int* __restrict__ src,
                                                 const int* __restrict__ dst,
                                                 int* __restrict__ cursor,
                                                 int* __restrict__ csr) {
  int i = blockIdx.x * 256 + threadIdx.x;
  if (i < NEDGES) {
    int p = atomicAdd(&cursor[dst[i]], 1);
    csr[p] = src[i];
  }
}

// ---------------- GIN aggregation (float4, 8 nodes/block) ----------------

__global__ __launch_bounds__(256) void k_agg(const float* __restrict__ h,
                                             const int* __restrict__ offs,
                                             const int* __restrict__ csr,
                                             const float* __restrict__ epsp, int layer,
                                             float* __restrict__ agg) {
  int node = blockIdx.x * 8 + (threadIdx.x >> 5);
  int lane = threadIdx.x & 31;  // float4 index within row
  const float4* h4 = (const float4*)h;
  float eps1 = 1.0f + epsp[layer];
  int s = offs[node], e = offs[node + 1];
  float4 hv = h4[node * 32 + lane];
  float4 a0, a1;
  a0.x = eps1 * hv.x; a0.y = eps1 * hv.y; a0.z = eps1 * hv.z; a0.w = eps1 * hv.w;
  a1.x = 0.f; a1.y = 0.f; a1.z = 0.f; a1.w = 0.f;
  int j = s;
  for (; j + 1 < e; j += 2) {
    int s0 = csr[j], s1 = csr[j + 1];
    float4 v0 = h4[s0 * 32 + lane];
    float4 v1 = h4[s1 * 32 + lane];
    a0.x += v0.x; a0.y += v0.y; a0.z += v0.z; a0.w += v0.w;
    a1.x += v1.x; a1.y += v1.y; a1.z += v1.z; a1.w += v1.w;
  }
  if (j < e) {
    float4 v = h4[csr[j] * 32 + lane];
    a0.x += v.x; a0.y += v.y; a0.z += v.z; a0.w += v.w;
  }
  a0.x += a1.x; a0.y += a1.y; a0.z += a1.z; a0.w += a1.w;
  ((float4*)agg)[node * 32 + lane] = a0;
}

// ---------------- Fused MLP: register-tiled 4 cols x 4 rows / thread ----------------

#define MROWS 32

__global__ __launch_bounds__(256) void k_mlp(const float* __restrict__ agg,
                                             const float* __restrict__ W1,
                                             const float* __restrict__ b1,
                                             const float* __restrict__ gamma,
                                             const float* __restrict__ beta,
                                             const float* __restrict__ rmean,
                                             const float* __restrict__ rvar,
                                             const float* __restrict__ W2,
                                             const float* __restrict__ b2,
                                             float* __restrict__ hout) {
  __shared__ float rbuf[MROWS][DIM];  // 16KB, reused as zbuf
  int t = threadIdx.x;
  int c0 = (t & 31) * 4;   // 4 contiguous output columns
  int rg = t >> 5;         // row group 0..7, rows rg*4 .. rg*4+3
  int r0 = blockIdx.x * MROWS;
  int nr = NNODES - r0; if (nr > MROWS) nr = MROWS;

  // stage agg rows as float4, zero-fill tail rows
  {
    float4* rb4 = (float4*)rbuf;
    const float4* ag4 = (const float4*)(agg + (size_t)r0 * DIM);
    int lim = nr * 32;
#pragma unroll
    for (int it = 0; it < 4; ++it) {
      int i = t + it * 256;
      float4 v; v.x = 0.f; v.y = 0.f; v.z = 0.f; v.w = 0.f;
      if (i < lim) v = ag4[i];
      rb4[i] = v;
    }
  }

  // per-column constants
  float4 bias1 = *(const float4*)&b1[c0];
  float4 g4 = *(const float4*)&gamma[c0];
  float4 be4 = *(const float4*)&beta[c0];
  float4 rm4 = *(const float4*)&rmean[c0];
  float4 rv4 = *(const float4*)&rvar[c0];
  float4 bsc, bsh;
  bsc.x = g4.x * rsqrtf(rv4.x + 1e-5f);
  bsc.y = g4.y * rsqrtf(rv4.y + 1e-5f);
  bsc.z = g4.z * rsqrtf(rv4.z + 1e-5f);
  bsc.w = g4.w * rsqrtf(rv4.w + 1e-5f);
  bsh.x = be4.x - rm4.x * bsc.x;
  bsh.y = be4.y - rm4.y * bsc.y;
  bsh.z = be4.z - rm4.z * bsc.z;
  bsh.w = be4.w - rm4.w * bsc.w;
  float4 bias2 = *(const float4*)&b2[c0];

  __syncthreads();

  // ---- GEMM1: acc[r][c] = sum_k rbuf[row][k] * W1[k][c] ----
  float4 acc[4];
#pragma unroll
  for (int r = 0; r < 4; ++r) acc[r] = bias1;
#pragma unroll 4
  for (int k4 = 0; k4 < 32; ++k4) {
    float4 w0 = *(const float4*)&W1[(k4 * 4 + 0) * DIM + c0];
    float4 w1 = *(const float4*)&W1[(k4 * 4 + 1) * DIM + c0];
    float4 w2 = *(const float4*)&W1[(k4 * 4 + 2) * DIM + c0];
    float4 w3 = *(const float4*)&W1[(k4 * 4 + 3) * DIM + c0];
#pragma unroll
    for (int r = 0; r < 4; ++r) {
      float4 a = *(float4*)&rbuf[rg * 4 + r][k4 * 4];
      acc[r].x = fmaf(a.x, w0.x, acc[r].x); acc[r].y = fmaf(a.x, w0.y, acc[r].y);
      acc[r].z = fmaf(a.x, w0.z, acc[r].z); acc[r].w = fmaf(a.x, w0.w, acc[r].w);
      acc[r].x = fmaf(a.y, w1.x, acc[r].x); acc[r].y = fmaf(a.y, w1.y, acc[r].y);
      acc[r].z = fmaf(a.y, w1.z, acc[r].z); acc[r].w = fmaf(a.y, w1.w, acc[r].w);
      acc[r].x = fmaf(a.z, w2.x, acc[r].x); acc[r].y = fmaf(a.z, w2.y, acc[r].y);
      acc[r].z = fmaf(a.z, w2.z, acc[r].z); acc[r].w = fmaf(a.z, w2.w, acc[r].w);
      acc[r].x = fmaf(a.w, w3.x, acc[r].x); acc[r].y = fmaf(a.w, w3.y, acc[r].y);
      acc[r].z = fmaf(a.w, w3.z, acc[r].z); acc[r].w = fmaf(a.w, w3.w, acc[r].w);
    }
  }

  // BN + ReLU, then write z into rbuf (reused)
  __syncthreads();  // all GEMM1 reads of rbuf done
#pragma unroll
  for (int r = 0; r < 4; ++r) {
    float4 z;
    z.x = fmaxf(fmaf(acc[r].x, bsc.x, bsh.x), 0.f);
    z.y = fmaxf(fmaf(acc[r].y, bsc.y, bsh.y), 0.f);
    z.z = fmaxf(fmaf(acc[r].z, bsc.z, bsh.z), 0.f);
    z.w = fmaxf(fmaf(acc[r].w, bsc.w, bsh.w), 0.f);
    *(float4*)&rbuf[rg * 4 + r][c0] = z;
  }
  __syncthreads();

  // ---- GEMM2 ----
  float4 acc2[4];
#pragma unroll
  for (int r = 0; r < 4; ++r) acc2[r] = bias2;
#pragma unroll 4
  for (int k4 = 0; k4 < 32; ++k4) {
    float4 w0 = *(const float4*)&W2[(k4 * 4 + 0) * DIM + c0];
    float4 w1 = *(const float4*)&W2[(k4 * 4 + 1) * DIM + c0];
    float4 w2 = *(const float4*)&W2[(k4 * 4 + 2) * DIM + c0];
    float4 w3 = *(const float4*)&W2[(k4 * 4 + 3) * DIM + c0];
#pragma unroll
    for (int r = 0; r < 4; ++r) {
      float4 a = *(float4*)&rbuf[rg * 4 + r][k4 * 4];
      acc2[r].x = fmaf(a.x, w0.x, acc2[r].x); acc2[r].y = fmaf(a.x, w0.y, acc2[r].y);
      acc2[r].z = fmaf(a.x, w0.z, acc2[r].z); acc2[r].w = fmaf(a.x, w0.w, acc2[r].w);
      acc2[r].x = fmaf(a.y, w1.x, acc2[r].x); acc2[r].y = fmaf(a.y, w1.y, acc2[r].y);
      acc2[r].z = fmaf(a.y, w1.z, acc2[r].z); acc2[r].w = fmaf(a.y, w1.w, acc2[r].w);
      acc2[r].x = fmaf(a.z, w2.x, acc2[r].x); acc2[r].y = fmaf(a.z, w2.y, acc2[r].y);
      acc2[r].z = fmaf(a.z, w2.z, acc2[r].z); acc2[r].w = fmaf(a.z, w2.w, acc2[r].w);
      acc2[r].x = fmaf(a.w, w3.x, acc2[r].x); acc2[r].y = fmaf(a.w, w3.y, acc2[r].y);
      acc2[r].z = fmaf(a.w, w3.z, acc2[r].z); acc2[r].w = fmaf(a.w, w3.w, acc2[r].w);
    }
  }

  // ReLU + store
#pragma unroll
  for (int r = 0; r < 4; ++r) {
    int row = rg * 4 + r;
    if (row < nr) {
      float4 z;
      z.x = fmaxf(acc2[r].x, 0.f); z.y = fmaxf(acc2[r].y, 0.f);
      z.z = fmaxf(acc2[r].z, 0.f); z.w = fmaxf(acc2[r].w, 0.f);
      *(float4*)&hout[(size_t)(r0 + row) * DIM + c0] = z;
    }
  }
}

// ---------------- mean-pool per graph + final linear ----------------

__device__ inline int lower_bound_i(const int* a, int n, int key) {
  int lo = 0, hi = n;
  while (lo < hi) {
    int m = (lo + hi) >> 1;
    if (a[m] < key) lo = m + 1; else hi = m;
  }
  return lo;
}

__global__ __launch_bounds__(256) void k_pool(const float* __restrict__ h,
                                              const int* __restrict__ batch,
                                              const float* __restrict__ Wout,
                                              const float* __restrict__ bout,
                                              float* __restrict__ out) {
  int g = blockIdx.x;
  int t = threadIdx.x;
  int f2 = t & 63;   // float2 index 0..63
  int st = t >> 6;   // stream 0..3
  int lo = lower_bound_i(batch, NNODES, g);
  int hi = lower_bound_i(batch, NNODES, g + 1);
  const float2* h2 = (const float2*)h;
  float2 a0, a1;
  a0.x = 0.f; a0.y = 0.f; a1.x = 0.f; a1.y = 0.f;
  int i = lo + st;
  for (; i + 4 < hi; i += 8) {
    float2 v0 = h2[(size_t)i * 64 + f2];
    float2 v1 = h2[(size_t)(i + 4) * 64 + f2];
    a0.x += v0.x; a0.y += v0.y;
    a1.x += v1.x; a1.y += v1.y;
  }
  if (i < hi) {
    float2 v = h2[(size_t)i * 64 + f2];
    a0.x += v.x; a0.y += v.y;
  }
  a0.x += a1.x; a0.y += a1.y;

  __shared__ float2 red[4][64];
  __shared__ float pooled[DIM];
  red[st][f2] = a0;
  __syncthreads();
  if (st == 0) {
    float2 s = red[0][f2];
    float2 s1 = red[1][f2], s2 = red[2][f2], s3 = red[3][f2];
    s.x += s1.x + s2.x + s3.x;
    s.y += s1.y + s2.y + s3.y;
    float cnt = (hi > lo) ? (float)(hi - lo) : 1.0f;
    pooled[f2 * 2] = s.x / cnt;
    pooled[f2 * 2 + 1] = s.y / cnt;
  }
  __syncthreads();
  if (t < DOUT) {
    float acc = bout[t];
#pragma unroll 8
    for (int k = 0; k < DIM; ++k) acc = fmaf(pooled[k], Wout[k * DOUT + t], acc);
    out[g * DOUT + t] = acc;
  }
}

// ---------------- launch ----------------

extern "C" void kernel_launch(void* const* d_in, const int* in_sizes, int n_in,
                              void* d_out, int out_size, void* d_ws, size_t ws_size,
                              hipStream_t stream) {
  const float* x     = (const float*)d_in[0];
  const int*   ei    = (const int*)d_in[1];
  const int*   batch = (const int*)d_in[2];
  const float* W1    = (const float*)d_in[3];
  const float* b1    = (const float*)d_in[4];
  const float* gamma = (const float*)d_in[5];
  const float* beta  = (const float*)d_in[6];
  const float* rmean = (const float*)d_in[7];
  const float* rvar  = (const float*)d_in[8];
  const float* W2    = (const float*)d_in[9];
  const float* b2    = (const float*)d_in[10];
  const float* eps   = (const float*)d_in[11];
  const float* Wout  = (const float*)d_in[12];
  const float* bout  = (const float*)d_in[13];
  float* out = (float*)d_out;

  const int* src = ei;
  const int* dst = ei + NEDGES;

  char* ws = (char*)d_ws;
  size_t o = 0;
  auto alloc = [&](size_t bytes) -> void* {
    o = (o + 255) & ~(size_t)255;
    void* p = ws + o;
    o += bytes;
    return p;
  };
  int*   deg    = (int*)alloc(NNODES * sizeof(int));
  int*   offs   = (int*)alloc((NNODES + 1) * sizeof(int));
  int*   cursor = (int*)alloc(NNODES * sizeof(int));
  int*   csr    = (int*)alloc(NEDGES * sizeof(int));
  float* agg    = (float*)alloc((size_t)NNODES * DIM * sizeof(float));
  float* hA     = (float*)alloc((size_t)NNODES * DIM * sizeof(float));
  float* hB     = (float*)alloc((size_t)NNODES * DIM * sizeof(float));

  hipMemsetAsync(deg, 0, NNODES * sizeof(int), stream);
  k_deg<<<(NEDGES + 255) / 256, 256, 0, stream>>>(dst, deg);
  k_scan<<<1, 1024, 0, stream>>>(deg, offs, cursor);
  k_scatter<<<(NEDGES + 255) / 256, 256, 0, stream>>>(src, dst, cursor, csr);

  const float* hin = x;
  float* houts[3] = {hA, hB, hA};
  for (int l = 0; l < 3; ++l) {
    k_agg<<<(NNODES + 7) / 8, 256, 0, stream>>>(hin, offs, csr, eps, l, agg);
    k_mlp<<<(NNODES + MROWS - 1) / MROWS, 256, 0, stream>>>(
        agg, W1 + (size_t)l * DIM * DIM, b1 + l * DIM, gamma + l * DIM,
        beta + l * DIM, rmean + l * DIM, rvar + l * DIM,
        W2 + (size_t)l * DIM * DIM, b2 + l * DIM, houts[l]);
    hin = houts[l];
  }
  k_pool<<<NGRAPHS, 256, 0, stream>>>(hin, batch, Wout, bout, out);
}

// Round 3
// 255.777 us; speedup vs baseline: 1.9198x; 1.5058x over previous
//
#include <hip/hip_runtime.h>
#include <hip/hip_bf16.h>

#define NNODES 25000
#define NEDGES 400000
#define DIM 128
#define NGRAPHS 512
#define DOUT 10
#define NPAD 32768   // padded node count for scan (1024 threads * 32)

typedef short bf16x8 __attribute__((ext_vector_type(8)));   // 8 bf16 in 4 VGPRs
typedef float f32x4 __attribute__((ext_vector_type(4)));

__device__ inline float bfu_lo(unsigned int u) {
  union { unsigned int i; float f; } v; v.i = u << 16; return v.f;
}
__device__ inline float bfu_hi(unsigned int u) {
  union { unsigned int i; float f; } v; v.i = u & 0xffff0000u; return v.f;
}
__device__ inline unsigned short f2bf(float f) {
  union { float f; unsigned int i; } v; v.f = f;
  unsigned int r = v.i + 0x7fff + ((v.i >> 16) & 1);
  return (unsigned short)(r >> 16);
}

// ---------------- CSR build ----------------

__global__ __launch_bounds__(256) void k_deg(const int* __restrict__ dst,
                                             int* __restrict__ deg) {
  int i = blockIdx.x * 256 + threadIdx.x;
  if (i < NEDGES) atomicAdd(&deg[dst[i]], 1);
}

// deg padded with zeros to NPAD; vectorized scan, int4 in/out
__global__ __launch_bounds__(1024) void k_scan(const int* __restrict__ deg,
                                               int* __restrict__ offs,
                                               int* __restrict__ cursor) {
  __shared__ int tsum[1024];
  int t = threadIdx.x;
  const int4* d4 = (const int4*)(deg + t * 32);
  int4 v[8];
#pragma unroll
  for (int j = 0; j < 8; ++j) v[j] = d4[j];
  int s = 0;
#pragma unroll
  for (int j = 0; j < 8; ++j) s += v[j].x + v[j].y + v[j].z + v[j].w;
  tsum[t] = s;
  __syncthreads();
  for (int off = 1; off < 1024; off <<= 1) {
    int u = (t >= off) ? tsum[t - off] : 0;
    __syncthreads();
    tsum[t] += u;
    __syncthreads();
  }
  int run = (t == 0) ? 0 : tsum[t - 1];
  int4* o4 = (int4*)(offs + t * 32);
  int4* c4 = (int4*)(cursor + t * 32);
#pragma unroll
  for (int j = 0; j < 8; ++j) {
    int4 w;
    w.x = run; run += v[j].x;
    w.y = run; run += v[j].y;
    w.z = run; run += v[j].z;
    w.w = run; run += v[j].w;
    o4[j] = w; c4[j] = w;
  }
  // offs[25000] is covered by the int4 stores (prefix stays NEDGES past 25000)
}

__global__ __launch_bounds__(256) void k_scatter(const int* __restrict__ src,
                                                 const int* __restrict__ dst,
                                                 int* __restrict__ cursor,
                                                 int* __restrict__ csr) {
  int i = blockIdx.x * 256 + threadIdx.x;
  if (i < NEDGES) {
    int p = atomicAdd(&cursor[dst[i]], 1);
    csr[p] = src[i];
  }
}

// ---------------- convert x f32 -> bf16 ----------------

__global__ __launch_bounds__(256) void k_cvt(const float* __restrict__ x,
                                             unsigned short* __restrict__ h0) {
  int i = blockIdx.x * 256 + threadIdx.x;     // 8 elems per thread
  if (i * 8 >= NNODES * DIM) return;
  const float4* x4 = (const float4*)x;
  float4 a = x4[i * 2], b = x4[i * 2 + 1];
  uint4 p;
  p.x = ((unsigned int)f2bf(a.y) << 16) | f2bf(a.x);
  p.y = ((unsigned int)f2bf(a.w) << 16) | f2bf(a.z);
  p.z = ((unsigned int)f2bf(b.y) << 16) | f2bf(b.x);
  p.w = ((unsigned int)f2bf(b.w) << 16) | f2bf(b.z);
  ((uint4*)h0)[i] = p;
}

// ---------------- transpose weights to bf16: WT[c][k] = W[k][c] ----------------

__global__ __launch_bounds__(256) void k_wprep(const float* __restrict__ W1,
                                               const float* __restrict__ W2,
                                               unsigned short* __restrict__ W1T,
                                               unsigned short* __restrict__ W2T) {
  int b = blockIdx.x;       // 0..5: layer = b>>1, which = b&1
  int l = b >> 1;
  const float* in = ((b & 1) ? W2 : W1) + (size_t)l * DIM * DIM;
  unsigned short* out = ((b & 1) ? W2T : W1T) + (size_t)l * DIM * DIM;
  for (int idx = threadIdx.x; idx < DIM * DIM; idx += 256) {
    int c = idx >> 7, k = idx & 127;
    out[idx] = f2bf(in[k * DIM + c]);
  }
}

// ---------------- GIN aggregation, bf16 in/out, f32 accum ----------------

__global__ __launch_bounds__(256) void k_agg(const unsigned short* __restrict__ h,
                                             const int* __restrict__ offs,
                                             const int* __restrict__ csr,
                                             const float* __restrict__ epsp, int layer,
                                             unsigned short* __restrict__ agg) {
  int node = blockIdx.x * 8 + (threadIdx.x >> 5);
  int lane = threadIdx.x & 31;      // 8B unit: 4 bf16 cols
  const uint2* h2 = (const uint2*)h;
  float eps1 = 1.0f + epsp[layer];
  int s = offs[node], e = offs[node + 1];
  uint2 hv = h2[(size_t)node * 32 + lane];
  float a0 = eps1 * bfu_lo(hv.x), a1 = eps1 * bfu_hi(hv.x);
  float a2 = eps1 * bfu_lo(hv.y), a3 = eps1 * bfu_hi(hv.y);
  float b0 = 0.f, b1 = 0.f, b2 = 0.f, b3 = 0.f;
  int j = s;
  for (; j + 3 < e; j += 4) {
    int s0 = csr[j], s1 = csr[j + 1], s2 = csr[j + 2], s3 = csr[j + 3];
    uint2 v0 = h2[(size_t)s0 * 32 + lane];
    uint2 v1 = h2[(size_t)s1 * 32 + lane];
    uint2 v2 = h2[(size_t)s2 * 32 + lane];
    uint2 v3 = h2[(size_t)s3 * 32 + lane];
    a0 += bfu_lo(v0.x); a1 += bfu_hi(v0.x); a2 += bfu_lo(v0.y); a3 += bfu_hi(v0.y);
    b0 += bfu_lo(v1.x); b1 += bfu_hi(v1.x); b2 += bfu_lo(v1.y); b3 += bfu_hi(v1.y);
    a0 += bfu_lo(v2.x); a1 += bfu_hi(v2.x); a2 += bfu_lo(v2.y); a3 += bfu_hi(v2.y);
    b0 += bfu_lo(v3.x); b1 += bfu_hi(v3.x); b2 += bfu_lo(v3.y); b3 += bfu_hi(v3.y);
  }
  for (; j < e; ++j) {
    uint2 v = h2[(size_t)csr[j] * 32 + lane];
    a0 += bfu_lo(v.x); a1 += bfu_hi(v.x); a2 += bfu_lo(v.y); a3 += bfu_hi(v.y);
  }
  a0 += b0; a1 += b1; a2 += b2; a3 += b3;
  uint2 p;
  p.x = ((unsigned int)f2bf(a1) << 16) | f2bf(a0);
  p.y = ((unsigned int)f2bf(a3) << 16) | f2bf(a2);
  ((uint2*)agg)[(size_t)node * 32 + lane] = p;
}

// ---------------- Fused MLP via MFMA bf16 ----------------
// Block: 256 thr (4 waves), 32 rows x 128 cols. Wave w owns cols w*32..w*32+31.
// A staged in LDS, XOR-swizzled (byte ^= (row&7)<<4 on 16B units).
// B fragments preloaded from transposed bf16 weights (contiguous K).

#define MROWS 32

__global__ __launch_bounds__(256) void k_mlp(const unsigned short* __restrict__ agg,
                                             const unsigned short* __restrict__ W1T,
                                             const unsigned short* __restrict__ W2T,
                                             const float* __restrict__ b1,
                                             const float* __restrict__ gamma,
                                             const float* __restrict__ beta,
                                             const float* __restrict__ rmean,
                                             const float* __restrict__ rvar,
                                             const float* __restrict__ b2,
                                             unsigned short* __restrict__ hout) {
  __shared__ __align__(16) char smem[MROWS * 256];   // 8KB, bf16 rows of 256B
  int t = threadIdx.x;
  int lane = t & 63;
  int wv = t >> 6;
  int r0 = blockIdx.x * MROWS;
  int cl = lane & 15;     // col / row within 16-tile
  int kg = lane >> 4;     // k-group 0..3

  // ---- stage agg rows (bf16) into swizzled LDS ----
  {
    const uint4* ag4 = (const uint4*)(agg + (size_t)r0 * DIM);
#pragma unroll
    for (int it = 0; it < 2; ++it) {
      int u = t + it * 256;             // 16B unit id; row = u/16
      int row = u >> 4, un = u & 15;
      uint4 v = make_uint4(0u, 0u, 0u, 0u);
      if (r0 + row < NNODES) v = ag4[u];
      *(uint4*)(smem + row * 256 + ((un * 16) ^ ((row & 7) << 4))) = v;
    }
  }

  // ---- preload B fragments for both GEMMs ----
  bf16x8 b1f[2][4], b2f[2][4];
#pragma unroll
  for (int ct = 0; ct < 2; ++ct) {
    int col = wv * 32 + ct * 16 + cl;
    const char* p1 = (const char*)(W1T + (size_t)col * DIM);
    const char* p2 = (const char*)(W2T + (size_t)col * DIM);
#pragma unroll
    for (int kk = 0; kk < 4; ++kk) {
      b1f[ct][kk] = *(const bf16x8*)(p1 + kk * 64 + kg * 16);
      b2f[ct][kk] = *(const bf16x8*)(p2 + kk * 64 + kg * 16);
    }
  }
  // per-col BN constants folded: z = relu(gemm*s1 + o1)
  float s1c[2], o1c[2], b2c[2];
#pragma unroll
  for (int ct = 0; ct < 2; ++ct) {
    int col = wv * 32 + ct * 16 + cl;
    float sc = gamma[col] * rsqrtf(rvar[col] + 1e-5f);
    s1c[ct] = sc;
    o1c[ct] = (b1[col] - rmean[col]) * sc + beta[col];
    b2c[ct] = b2[col];
  }
  __syncthreads();

  // ---- GEMM1 ----
  f32x4 zero = {0.f, 0.f, 0.f, 0.f};
  f32x4 acc[2][2] = {{zero, zero}, {zero, zero}};
#pragma unroll
  for (int kk = 0; kk < 4; ++kk) {
#pragma unroll
    for (int rt = 0; rt < 2; ++rt) {
      int row = rt * 16 + cl;
      int un = kk * 4 + kg;
      bf16x8 a = *(const bf16x8*)(smem + row * 256 + ((un * 16) ^ ((row & 7) << 4)));
      acc[rt][0] = __builtin_amdgcn_mfma_f32_16x16x32_bf16(a, b1f[0][kk], acc[rt][0], 0, 0, 0);
      acc[rt][1] = __builtin_amdgcn_mfma_f32_16x16x32_bf16(a, b1f[1][kk], acc[rt][1], 0, 0, 0);
    }
  }
  __syncthreads();   // all A reads done before overwriting with z

  // ---- epilogue1: z = relu(acc*s1 + o1) -> bf16 -> LDS (same swizzle) ----
#pragma unroll
  for (int rt = 0; rt < 2; ++rt)
#pragma unroll
    for (int ct = 0; ct < 2; ++ct) {
      int col = wv * 32 + ct * 16 + cl;
#pragma unroll
      for (int j = 0; j < 4; ++j) {
        int row = rt * 16 + kg * 4 + j;   // C/D layout: row=(lane>>4)*4+j, col=lane&15
        float z = fmaxf(acc[rt][ct][j] * s1c[ct] + o1c[ct], 0.f);
        *(unsigned short*)(smem + row * 256 + ((col * 2) ^ ((row & 7) << 4))) = f2bf(z);
      }
    }
  __syncthreads();

  // ---- GEMM2 ----
  f32x4 acc2[2][2] = {{zero, zero}, {zero, zero}};
#pragma unroll
  for (int kk = 0; kk < 4; ++kk) {
#pragma unroll
    for (int rt = 0; rt < 2; ++rt) {
      int row = rt * 16 + cl;
      int un = kk * 4 + kg;
      bf16x8 a = *(const bf16x8*)(smem + row * 256 + ((un * 16) ^ ((row & 7) << 4)));
      acc2[rt][0] = __builtin_amdgcn_mfma_f32_16x16x32_bf16(a, b2f[0][kk], acc2[rt][0], 0, 0, 0);
      acc2[rt][1] = __builtin_amdgcn_mfma_f32_16x16x32_bf16(a, b2f[1][kk], acc2[rt][1], 0, 0, 0);
    }
  }
  __syncthreads();

  // ---- epilogue2: h = relu(acc2 + b2) -> bf16 -> LDS ----
#pragma unroll
  for (int rt = 0; rt < 2; ++rt)
#pragma unroll
    for (int ct = 0; ct < 2; ++ct) {
      int col = wv * 32 + ct * 16 + cl;
#pragma unroll
      for (int j = 0; j < 4; ++j) {
        int row = rt * 16 + kg * 4 + j;
        float hv = fmaxf(acc2[rt][ct][j] + b2c[ct], 0.f);
        *(unsigned short*)(smem + row * 256 + ((col * 2) ^ ((row & 7) << 4))) = f2bf(hv);
      }
    }
  __syncthreads();

  // ---- de-swizzle copy out ----
  {
    uint4* ho4 = (uint4*)(hout + (size_t)r0 * DIM);
#pragma unroll
    for (int it = 0; it < 2; ++it) {
      int u = t + it * 256;
      int row = u >> 4, un = u & 15;
      if (r0 + row < NNODES) {
        uint4 v = *(const uint4*)(smem + row * 256 + ((un * 16) ^ ((row & 7) << 4)));
        ho4[u] = v;
      }
    }
  }
}

// ---------------- mean-pool + final linear ----------------

__device__ inline int lower_bound_i(const int* a, int n, int key) {
  int lo = 0, hi = n;
  while (lo < hi) {
    int m = (lo + hi) >> 1;
    if (a[m] < key) lo = m + 1; else hi = m;
  }
  return lo;
}

__global__ __launch_bounds__(256) void k_pool(const unsigned short* __restrict__ h,
                                              const int* __restrict__ batch,
                                              const float* __restrict__ Wout,
                                              const float* __restrict__ bout,
                                              float* __restrict__ out) {
  int g = blockIdx.x;
  int t = threadIdx.x;
  int cg = t & 31;    // 8B col group (4 cols)
  int st = t >> 5;    // stream 0..7
  int lo = lower_bound_i(batch, NNODES, g);
  int hi = lower_bound_i(batch, NNODES, g + 1);
  const uint2* h2 = (const uint2*)h;
  float a0 = 0.f, a1 = 0.f, a2 = 0.f, a3 = 0.f;
  for (int i = lo + st; i < hi; i += 8) {
    uint2 v = h2[(size_t)i * 32 + cg];
    a0 += bfu_lo(v.x); a1 += bfu_hi(v.x); a2 += bfu_lo(v.y); a3 += bfu_hi(v.y);
  }
  __shared__ float red[8][DIM];
  __shared__ float pooled[DIM];
  red[st][cg * 4 + 0] = a0; red[st][cg * 4 + 1] = a1;
  red[st][cg * 4 + 2] = a2; red[st][cg * 4 + 3] = a3;
  __syncthreads();
  if (t < DIM) {
    float s = 0.f;
#pragma unroll
    for (int k = 0; k < 8; ++k) s += red[k][t];
    float cnt = (hi > lo) ? (float)(hi - lo) : 1.0f;
    pooled[t] = s / cnt;
  }
  __syncthreads();
  if (t < DOUT) {
    float acc = bout[t];
#pragma unroll 8
    for (int k = 0; k < DIM; ++k) acc = fmaf(pooled[k], Wout[k * DOUT + t], acc);
    out[g * DOUT + t] = acc;
  }
}

// ---------------- launch ----------------

extern "C" void kernel_launch(void* const* d_in, const int* in_sizes, int n_in,
                              void* d_out, int out_size, void* d_ws, size_t ws_size,
                              hipStream_t stream) {
  const float* x     = (const float*)d_in[0];
  const int*   ei    = (const int*)d_in[1];
  const int*   batch = (const int*)d_in[2];
  const float* W1    = (const float*)d_in[3];
  const float* b1    = (const float*)d_in[4];
  const float* gamma = (const float*)d_in[5];
  const float* beta  = (const float*)d_in[6];
  const float* rmean = (const float*)d_in[7];
  const float* rvar  = (const float*)d_in[8];
  const float* W2    = (const float*)d_in[9];
  const float* b2    = (const float*)d_in[10];
  const float* eps   = (const float*)d_in[11];
  const float* Wout  = (const float*)d_in[12];
  const float* bout  = (const float*)d_in[13];
  float* out = (float*)d_out;

  const int* src = ei;
  const int* dst = ei + NEDGES;

  char* ws = (char*)d_ws;
  size_t o = 0;
  auto alloc = [&](size_t bytes) -> void* {
    o = (o + 255) & ~(size_t)255;
    void* p = ws + o;
    o += bytes;
    return p;
  };
  int* deg    = (int*)alloc(NPAD * sizeof(int));
  int* offs   = (int*)alloc((NPAD + 8) * sizeof(int));
  int* cursor = (int*)alloc(NPAD * sizeof(int));
  int* csr    = (int*)alloc(NEDGES * sizeof(int));
  unsigned short* h0  = (unsigned short*)alloc((size_t)NNODES * DIM * 2);
  unsigned short* agg = (unsigned short*)alloc((size_t)NNODES * DIM * 2);
  unsigned short* hA  = (unsigned short*)alloc((size_t)NNODES * DIM * 2);
  unsigned short* hB  = (unsigned short*)alloc((size_t)NNODES * DIM * 2);
  unsigned short* W1T = (unsigned short*)alloc(3 * DIM * DIM * 2);
  unsigned short* W2T = (unsigned short*)alloc(3 * DIM * DIM * 2);

  hipMemsetAsync(deg, 0, NPAD * sizeof(int), stream);
  k_deg<<<(NEDGES + 255) / 256, 256, 0, stream>>>(dst, deg);
  k_cvt<<<(NNODES * DIM / 8 + 255) / 256, 256, 0, stream>>>(x, h0);
  k_wprep<<<6, 256, 0, stream>>>(W1, W2, W1T, W2T);
  k_scan<<<1, 1024, 0, stream>>>(deg, offs, cursor);
  k_scatter<<<(NEDGES + 255) / 256, 256, 0, stream>>>(src, dst, cursor, csr);

  const unsigned short* hin = h0;
  unsigned short* houts[3] = {hA, hB, hA};
  for (int l = 0; l < 3; ++l) {
    k_agg<<<NNODES / 8, 256, 0, stream>>>(hin, offs, csr, eps, l, agg);
    k_mlp<<<(NNODES + MROWS - 1) / MROWS, 256, 0, stream>>>(
        agg, W1T + (size_t)l * DIM * DIM, W2T + (size_t)l * DIM * DIM,
        b1 + l * DIM, gamma + l * DIM, beta + l * DIM, rmean + l * DIM,
        rvar + l * DIM, b2 + l * DIM, houts[l]);
    hin = houts[l];
  }
  k_pool<<<NGRAPHS, 256, 0, stream>>>(hin, batch, Wout, bout, out);
}